// Round 1
// baseline (403.300 us; speedup 1.0000x reference)
//
#include <hip/hip_runtime.h>

constexpr int N_OBJ = 4096, N_REG = 8192, D = 512, GW = 128, NE = 131072;

// ---------- CSR offsets via binary search over sorted tgt ----------
__global__ void csr_offsets(const int* __restrict__ tgt, int* __restrict__ off,
                            int n_tgt, int ne) {
  int t = blockIdx.x * blockDim.x + threadIdx.x;
  if (t > n_tgt) return;
  int lo = 0, hi = ne;
  while (lo < hi) {
    int mid = (lo + hi) >> 1;
    if (tgt[mid] < t) lo = mid + 1; else hi = mid;
  }
  off[t] = lo;
}

// ---------- tiled fp32 GEMM: C[m][n] = sum_k act(A[m][k]) * B[n][k] (+res+bias) ----------
// A: [M,K] row-major (lda=K), B: [N,K] row-major (ldb), C: [M,N] (ldc=N)
template<bool RELU_A, bool EPI>
__global__ __launch_bounds__(256) void gemm_rowdot(
    const float* __restrict__ A, int lda,
    const float* __restrict__ B, int ldb,
    float* __restrict__ C, int ldc,
    const float* __restrict__ res, const float* __restrict__ bias, int K) {
  __shared__ float As[32][68];  // [k][m], pad 68 -> 272B rows (16B aligned)
  __shared__ float Bs[32][68];  // [k][n]
  const int tid = threadIdx.x;
  const int tx = tid & 15, ty = tid >> 4;
  const int m0 = blockIdx.y * 64, n0 = blockIdx.x * 64;
  float acc[4][4] = {};
  for (int k0 = 0; k0 < K; k0 += 32) {
#pragma unroll
    for (int i = 0; i < 2; ++i) {
      int lin = tid + i * 256;            // float4 index, 512 per tile
      int row = lin >> 3, c4 = (lin & 7) * 4;
      float4 va = *(const float4*)&A[(size_t)(m0 + row) * lda + k0 + c4];
      float4 vb = *(const float4*)&B[(size_t)(n0 + row) * ldb + k0 + c4];
      if (RELU_A) {
        va.x = fmaxf(va.x, 0.f); va.y = fmaxf(va.y, 0.f);
        va.z = fmaxf(va.z, 0.f); va.w = fmaxf(va.w, 0.f);
      }
      As[c4 + 0][row] = va.x; As[c4 + 1][row] = va.y;
      As[c4 + 2][row] = va.z; As[c4 + 3][row] = va.w;
      Bs[c4 + 0][row] = vb.x; Bs[c4 + 1][row] = vb.y;
      Bs[c4 + 2][row] = vb.z; Bs[c4 + 3][row] = vb.w;
    }
    __syncthreads();
#pragma unroll
    for (int kk = 0; kk < 32; ++kk) {
      float4 a = *(const float4*)&As[kk][ty * 4];
      float4 b = *(const float4*)&Bs[kk][tx * 4];
      const float av[4] = {a.x, a.y, a.z, a.w};
      const float bv[4] = {b.x, b.y, b.z, b.w};
#pragma unroll
      for (int i = 0; i < 4; ++i)
#pragma unroll
        for (int j = 0; j < 4; ++j) acc[i][j] += av[i] * bv[j];
    }
    __syncthreads();
  }
#pragma unroll
  for (int i = 0; i < 4; ++i) {
    int m = m0 + ty * 4 + i;
#pragma unroll
    for (int j = 0; j < 4; ++j) {
      int n = n0 + tx * 4 + j;
      float v = acc[i][j];
      if (EPI) v += res[(size_t)m * ldc + n] + bias[n];
      C[(size_t)m * ldc + n] = v;
    }
  }
}

// ---------- per-edge gate: mean_j sigmoid(PA[src][j] + PB[tgt][j] + gb[j]) ----------
// Half-wave (32 lanes) per edge: coalesced 512B row reads, 4 sigmoids/lane.
__global__ __launch_bounds__(256) void gate_kernel(
    const float* __restrict__ PA, const float* __restrict__ PB,
    const int* __restrict__ tgt, const int* __restrict__ src,
    const float* __restrict__ gb, float* __restrict__ gate) {
  const int tid = threadIdx.x;
  const int lane = tid & 31;
  const int e = blockIdx.x * 8 + (tid >> 5);
  const int t = tgt[e], s = src[e];
  float4 pa = *(const float4*)&PA[(size_t)s * GW + lane * 4];
  float4 pb = *(const float4*)&PB[(size_t)t * GW + lane * 4];
  float4 bb = *(const float4*)&gb[lane * 4];
  float sum = 1.f / (1.f + __expf(-(pa.x + pb.x + bb.x)))
            + 1.f / (1.f + __expf(-(pa.y + pb.y + bb.y)))
            + 1.f / (1.f + __expf(-(pa.z + pb.z + bb.z)))
            + 1.f / (1.f + __expf(-(pa.w + pb.w + bb.w)));
#pragma unroll
  for (int msk = 16; msk >= 1; msk >>= 1) sum += __shfl_xor(sum, msk, 64);
  if (lane == 0) gate[e] = sum * (1.0f / GW);
}

// ---------- per-target segment mean of gate-weighted src features ----------
__global__ __launch_bounds__(256) void segsum_kernel(
    const float* __restrict__ feat_src, const float* __restrict__ gate,
    const int* __restrict__ src, const int* __restrict__ off,
    float* __restrict__ m_out) {
  const int t = blockIdx.x, tid = threadIdx.x;
  const int e0 = off[t], e1 = off[t + 1];
  float acc0 = 0.f, acc1 = 0.f;
  for (int e = e0; e < e1; ++e) {
    float g = gate[e];
    int s = src[e];
    const float* f = feat_src + (size_t)s * D;
    acc0 += f[tid] * g;
    acc1 += f[tid + 256] * g;
  }
  float inv = 1.0f / fmaxf((float)(e1 - e0), 1.0f);
  m_out[(size_t)t * D + tid]       = acc0 * inv;
  m_out[(size_t)t * D + tid + 256] = acc1 * inv;
}

extern "C" void kernel_launch(void* const* d_in, const int* in_sizes, int n_in,
                              void* d_out, int out_size, void* d_ws, size_t ws_size,
                              hipStream_t stream) {
  const float* feat_obj = (const float*)d_in[0];
  const float* feat_reg = (const float*)d_in[1];
  const int*   r2o_tgt  = (const int*)d_in[2];
  const int*   r2o_src  = (const int*)d_in[3];
  const int*   o2r_tgt  = (const int*)d_in[4];
  const int*   o2r_src  = (const int*)d_in[5];
  const float* gw_r2o   = (const float*)d_in[6];
  const float* gb_r2o   = (const float*)d_in[7];
  const float* gw_o2r   = (const float*)d_in[8];
  const float* gb_o2r   = (const float*)d_in[9];
  const float* tw_r2o   = (const float*)d_in[10];
  const float* tb_r2o   = (const float*)d_in[11];
  const float* tw_o2r   = (const float*)d_in[12];
  const float* tb_o2r   = (const float*)d_in[13];
  float* out_obj = (float*)d_out;
  float* out_reg = out_obj + (size_t)N_OBJ * D;

  // bump allocator over d_ws (everything written before read, every call)
  size_t cur = 0;
  auto alloc = [&](size_t bytes) -> void* {
    cur = (cur + 255) & ~(size_t)255;
    void* p = (char*)d_ws + cur;
    cur += bytes;
    return p;
  };
  int*   off_r2o  = (int*)alloc((N_OBJ + 1) * sizeof(int));
  int*   off_o2r  = (int*)alloc((N_REG + 1) * sizeof(int));
  float* PA_r2o   = (float*)alloc((size_t)N_REG * GW * 4);  // relu(reg) @ gw_r2o[:, :512].T
  float* PB_r2o   = (float*)alloc((size_t)N_OBJ * GW * 4);  // relu(obj) @ gw_r2o[:, 512:].T
  float* PA_o2r   = (float*)alloc((size_t)N_OBJ * GW * 4);
  float* PB_o2r   = (float*)alloc((size_t)N_REG * GW * 4);
  float* gate_r2o = (float*)alloc((size_t)NE * 4);
  float* gate_o2r = (float*)alloc((size_t)NE * 4);
  float* m_obj    = (float*)alloc((size_t)N_OBJ * D * 4);
  float* m_reg    = (float*)alloc((size_t)N_REG * D * 4);

  csr_offsets<<<(N_OBJ + 256) / 256, 256, 0, stream>>>(r2o_tgt, off_r2o, N_OBJ, NE);
  csr_offsets<<<(N_REG + 256) / 256, 256, 0, stream>>>(o2r_tgt, off_o2r, N_REG, NE);

  // node-level gate projections (the algebraic factorization)
  gemm_rowdot<true,  false><<<dim3(GW / 64, N_REG / 64), 256, 0, stream>>>(
      feat_reg, D, gw_r2o,     2 * D, PA_r2o, GW, nullptr, nullptr, D);
  gemm_rowdot<true,  false><<<dim3(GW / 64, N_OBJ / 64), 256, 0, stream>>>(
      feat_obj, D, gw_r2o + D, 2 * D, PB_r2o, GW, nullptr, nullptr, D);
  gemm_rowdot<true,  false><<<dim3(GW / 64, N_OBJ / 64), 256, 0, stream>>>(
      feat_obj, D, gw_o2r,     2 * D, PA_o2r, GW, nullptr, nullptr, D);
  gemm_rowdot<true,  false><<<dim3(GW / 64, N_REG / 64), 256, 0, stream>>>(
      feat_reg, D, gw_o2r + D, 2 * D, PB_o2r, GW, nullptr, nullptr, D);

  gate_kernel<<<NE / 8, 256, 0, stream>>>(PA_r2o, PB_r2o, r2o_tgt, r2o_src, gb_r2o, gate_r2o);
  gate_kernel<<<NE / 8, 256, 0, stream>>>(PA_o2r, PB_o2r, o2r_tgt, o2r_src, gb_o2r, gate_o2r);

  segsum_kernel<<<N_OBJ, 256, 0, stream>>>(feat_reg, gate_r2o, r2o_src, off_r2o, m_obj);
  segsum_kernel<<<N_REG, 256, 0, stream>>>(feat_obj, gate_o2r, o2r_src, off_o2r, m_reg);

  // out = feat + relu(m) @ tw.T + tb
  gemm_rowdot<true, true><<<dim3(D / 64, N_OBJ / 64), 256, 0, stream>>>(
      m_obj, D, tw_r2o, D, out_obj, D, feat_obj, tb_r2o, D);
  gemm_rowdot<true, true><<<dim3(D / 64, N_REG / 64), 256, 0, stream>>>(
      m_reg, D, tw_o2r, D, out_reg, D, feat_reg, tb_o2r, D);
}

// Round 2
// 299.342 us; speedup vs baseline: 1.3473x; 1.3473x over previous
//
#include <hip/hip_runtime.h>

constexpr int N_OBJ = 4096, N_REG = 8192, D = 512, GW = 128, NE = 131072;

typedef __attribute__((ext_vector_type(8))) short short8;
typedef __attribute__((ext_vector_type(4))) float f32x4;

__device__ inline short f2bf(float f) {
  unsigned u = __builtin_bit_cast(unsigned, f);
  unsigned r = (u + 0x7FFF + ((u >> 16) & 1)) >> 16;
  return (short)r;
}

// ---------- CSR offsets via binary search over sorted tgt ----------
__global__ void csr_offsets(const int* __restrict__ tgt, int* __restrict__ off,
                            int n_tgt, int ne) {
  int t = blockIdx.x * blockDim.x + threadIdx.x;
  if (t > n_tgt) return;
  int lo = 0, hi = ne;
  while (lo < hi) {
    int mid = (lo + hi) >> 1;
    if (tgt[mid] < t) lo = mid + 1; else hi = mid;
  }
  off[t] = lo;
}

// ---------- cast fp32 -> bf16, optional relu, float4-vectorized ----------
template<bool RELU>
__global__ __launch_bounds__(256) void cast_bf16(const float* __restrict__ in,
                                                 short* __restrict__ out, int n4) {
  int i = blockIdx.x * 256 + threadIdx.x;
  if (i >= n4) return;
  float4 v = ((const float4*)in)[i];
  if (RELU) {
    v.x = fmaxf(v.x, 0.f); v.y = fmaxf(v.y, 0.f);
    v.z = fmaxf(v.z, 0.f); v.w = fmaxf(v.w, 0.f);
  }
  short4 o = make_short4(f2bf(v.x), f2bf(v.y), f2bf(v.z), f2bf(v.w));
  ((short4*)out)[i] = o;
}

// ---------- fused cast of the 4 weight matrices (one launch) ----------
// sizes in float4: gw 32768 each, tw 65536 each; total 196608
__global__ __launch_bounds__(256) void cast_weights(
    const float* __restrict__ w0, const float* __restrict__ w1,
    const float* __restrict__ w2, const float* __restrict__ w3,
    short* __restrict__ o0, short* __restrict__ o1,
    short* __restrict__ o2, short* __restrict__ o3) {
  int i = blockIdx.x * 256 + threadIdx.x;
  const float* src; short* dst; int j = i;
  if (j < 32768)       { src = w0; dst = o0; }
  else if (j < 65536)  { src = w1; dst = o1; j -= 32768; }
  else if (j < 131072) { src = w2; dst = o2; j -= 65536; }
  else                 { src = w3; dst = o3; j -= 131072; }
  float4 v = ((const float4*)src)[j];
  short4 o = make_short4(f2bf(v.x), f2bf(v.y), f2bf(v.z), f2bf(v.w));
  ((short4*)dst)[j] = o;
}

// ---------- bf16 MFMA GEMM: C[m][n] = sum_k A[m,k]*B[n,k] (+res+bias) ----------
// A: [M,K] bf16 row-major (lda), B: [N,K] bf16 row-major (ldb), C fp32 (ldc)
// 128x128 tile, BK=32, 4 waves (2x2 of 64x64), m97 structure.
template<bool EPI>
__global__ __launch_bounds__(256) void gemm_mfma(
    const short* __restrict__ A, int lda,
    const short* __restrict__ B, int ldb,
    float* __restrict__ C, int ldc,
    const float* __restrict__ res, const float* __restrict__ bias, int K) {
  __shared__ short As[128 * 32];
  __shared__ short Bs[128 * 32];
  const int tid = threadIdx.x;
  const int lane = tid & 63, w = tid >> 6;
  const int m0 = blockIdx.y * 128, n0 = blockIdx.x * 128;
  const int wm = (w >> 1) * 64, wn = (w & 1) * 64;
  const int sr = lane >> 2;          // staging row within 16-row group
  const int sc = (lane & 3) * 8;     // staging k-elem offset
  const int fr = lane & 15;          // fragment row
  const int fk = (lane >> 4) * 8;    // fragment k offset

  f32x4 acc[4][4];
#pragma unroll
  for (int i = 0; i < 4; ++i)
#pragma unroll
    for (int j = 0; j < 4; ++j) acc[i][j] = (f32x4){0.f, 0.f, 0.f, 0.f};

  for (int k0 = 0; k0 < K; k0 += 32) {
    // stage: wave w covers rows [32w, 32w+32) of both tiles, 2 instrs each
#pragma unroll
    for (int h = 0; h < 2; ++h) {
      int rg = w * 32 + h * 16;   // wave-uniform 16-row group start
      const short* ga = A + (size_t)(m0 + rg + sr) * lda + k0 + sc;
      const short* gb = B + (size_t)(n0 + rg + sr) * ldb + k0 + sc;
      __builtin_amdgcn_global_load_lds(
          (const __attribute__((address_space(1))) void*)ga,
          (__attribute__((address_space(3))) void*)&As[rg * 32], 16, 0, 0);
      __builtin_amdgcn_global_load_lds(
          (const __attribute__((address_space(1))) void*)gb,
          (__attribute__((address_space(3))) void*)&Bs[rg * 32], 16, 0, 0);
    }
    __syncthreads();
    short8 a[4], b[4];
#pragma unroll
    for (int i = 0; i < 4; ++i)
      a[i] = *(const short8*)&As[(wm + i * 16 + fr) * 32 + fk];
#pragma unroll
    for (int j = 0; j < 4; ++j)
      b[j] = *(const short8*)&Bs[(wn + j * 16 + fr) * 32 + fk];
#pragma unroll
    for (int i = 0; i < 4; ++i)
#pragma unroll
      for (int j = 0; j < 4; ++j)
        acc[i][j] = __builtin_amdgcn_mfma_f32_16x16x32_bf16(a[i], b[j], acc[i][j], 0, 0, 0);
    __syncthreads();
  }

#pragma unroll
  for (int i = 0; i < 4; ++i) {
#pragma unroll
    for (int j = 0; j < 4; ++j) {
      int n = n0 + wn + j * 16 + fr;
#pragma unroll
      for (int r = 0; r < 4; ++r) {
        int m = m0 + wm + i * 16 + (lane >> 4) * 4 + r;
        float v = acc[i][j][r];
        if (EPI) v += res[(size_t)m * ldc + n] + bias[n];
        C[(size_t)m * ldc + n] = v;
      }
    }
  }
}

// ---------- per-edge gate: mean_j sigmoid(PA[src][j] + PB[tgt][j] + gb[j]) ----------
__global__ __launch_bounds__(256) void gate_kernel(
    const float* __restrict__ PA, const float* __restrict__ PB,
    const int* __restrict__ tgt, const int* __restrict__ src,
    const float* __restrict__ gb, float* __restrict__ gate) {
  const int tid = threadIdx.x;
  const int lane = tid & 31;
  const int e = blockIdx.x * 8 + (tid >> 5);
  const int t = tgt[e], s = src[e];
  float4 pa = *(const float4*)&PA[(size_t)s * GW + lane * 4];
  float4 pb = *(const float4*)&PB[(size_t)t * GW + lane * 4];
  float4 bb = *(const float4*)&gb[lane * 4];
  float sum = 1.f / (1.f + __expf(-(pa.x + pb.x + bb.x)))
            + 1.f / (1.f + __expf(-(pa.y + pb.y + bb.y)))
            + 1.f / (1.f + __expf(-(pa.z + pb.z + bb.z)))
            + 1.f / (1.f + __expf(-(pa.w + pb.w + bb.w)));
#pragma unroll
  for (int msk = 16; msk >= 1; msk >>= 1) sum += __shfl_xor(sum, msk, 64);
  if (lane == 0) gate[e] = sum * (1.0f / GW);
}

// ---------- per-target segment mean; emits relu(m) as bf16 (GEMM A operand) ----------
__global__ __launch_bounds__(256) void segsum_kernel(
    const float* __restrict__ feat_src, const float* __restrict__ gate,
    const int* __restrict__ src, const int* __restrict__ off,
    short* __restrict__ m_out) {
  const int t = blockIdx.x, tid = threadIdx.x;
  const int e0 = off[t], e1 = off[t + 1];
  float acc0 = 0.f, acc1 = 0.f;
  for (int e = e0; e < e1; ++e) {
    float g = gate[e];
    int s = src[e];
    const float* f = feat_src + (size_t)s * D;
    acc0 += f[tid] * g;
    acc1 += f[tid + 256] * g;
  }
  float inv = 1.0f / fmaxf((float)(e1 - e0), 1.0f);
  m_out[(size_t)t * D + tid]       = f2bf(fmaxf(acc0 * inv, 0.f));
  m_out[(size_t)t * D + tid + 256] = f2bf(fmaxf(acc1 * inv, 0.f));
}

extern "C" void kernel_launch(void* const* d_in, const int* in_sizes, int n_in,
                              void* d_out, int out_size, void* d_ws, size_t ws_size,
                              hipStream_t stream) {
  const float* feat_obj = (const float*)d_in[0];
  const float* feat_reg = (const float*)d_in[1];
  const int*   r2o_tgt  = (const int*)d_in[2];
  const int*   r2o_src  = (const int*)d_in[3];
  const int*   o2r_tgt  = (const int*)d_in[4];
  const int*   o2r_src  = (const int*)d_in[5];
  const float* gw_r2o   = (const float*)d_in[6];
  const float* gb_r2o   = (const float*)d_in[7];
  const float* gw_o2r   = (const float*)d_in[8];
  const float* gb_o2r   = (const float*)d_in[9];
  const float* tw_r2o   = (const float*)d_in[10];
  const float* tb_r2o   = (const float*)d_in[11];
  const float* tw_o2r   = (const float*)d_in[12];
  const float* tb_o2r   = (const float*)d_in[13];
  float* out_obj = (float*)d_out;
  float* out_reg = out_obj + (size_t)N_OBJ * D;

  size_t cur = 0;
  auto alloc = [&](size_t bytes) -> void* {
    cur = (cur + 255) & ~(size_t)255;
    void* p = (char*)d_ws + cur;
    cur += bytes;
    return p;
  };
  int*   off_r2o  = (int*)alloc((N_OBJ + 1) * sizeof(int));
  int*   off_o2r  = (int*)alloc((N_REG + 1) * sizeof(int));
  short* bf_obj   = (short*)alloc((size_t)N_OBJ * D * 2);   // relu(feat_obj) bf16
  short* bf_reg   = (short*)alloc((size_t)N_REG * D * 2);   // relu(feat_reg) bf16
  short* bgw_r2o  = (short*)alloc((size_t)GW * 2 * D * 2);
  short* bgw_o2r  = (short*)alloc((size_t)GW * 2 * D * 2);
  short* btw_r2o  = (short*)alloc((size_t)D * D * 2);
  short* btw_o2r  = (short*)alloc((size_t)D * D * 2);
  float* PA_r2o   = (float*)alloc((size_t)N_REG * GW * 4);
  float* PB_r2o   = (float*)alloc((size_t)N_OBJ * GW * 4);
  float* PA_o2r   = (float*)alloc((size_t)N_OBJ * GW * 4);
  float* PB_o2r   = (float*)alloc((size_t)N_REG * GW * 4);
  float* gate_r2o = (float*)alloc((size_t)NE * 4);
  float* gate_o2r = (float*)alloc((size_t)NE * 4);
  short* m_obj    = (short*)alloc((size_t)N_OBJ * D * 2);   // relu(m) bf16
  short* m_reg    = (short*)alloc((size_t)N_REG * D * 2);

  csr_offsets<<<(N_OBJ + 256) / 256, 256, 0, stream>>>(r2o_tgt, off_r2o, N_OBJ, NE);
  csr_offsets<<<(N_REG + 256) / 256, 256, 0, stream>>>(o2r_tgt, off_o2r, N_REG, NE);

  cast_bf16<true><<<(N_OBJ * D / 4 + 255) / 256, 256, 0, stream>>>(feat_obj, bf_obj, N_OBJ * D / 4);
  cast_bf16<true><<<(N_REG * D / 4 + 255) / 256, 256, 0, stream>>>(feat_reg, bf_reg, N_REG * D / 4);
  cast_weights<<<196608 / 256, 256, 0, stream>>>(gw_r2o, gw_o2r, tw_r2o, tw_o2r,
                                                 bgw_r2o, bgw_o2r, btw_r2o, btw_o2r);

  // node-level gate projections: PA = relu(src_feat)@gw[:, :D].T, PB = relu(tgt_feat)@gw[:, D:].T
  gemm_mfma<false><<<dim3(GW / 128, N_REG / 128), 256, 0, stream>>>(
      bf_reg, D, bgw_r2o,     2 * D, PA_r2o, GW, nullptr, nullptr, D);
  gemm_mfma<false><<<dim3(GW / 128, N_OBJ / 128), 256, 0, stream>>>(
      bf_obj, D, bgw_r2o + D, 2 * D, PB_r2o, GW, nullptr, nullptr, D);
  gemm_mfma<false><<<dim3(GW / 128, N_OBJ / 128), 256, 0, stream>>>(
      bf_obj, D, bgw_o2r,     2 * D, PA_o2r, GW, nullptr, nullptr, D);
  gemm_mfma<false><<<dim3(GW / 128, N_REG / 128), 256, 0, stream>>>(
      bf_reg, D, bgw_o2r + D, 2 * D, PB_o2r, GW, nullptr, nullptr, D);

  gate_kernel<<<NE / 8, 256, 0, stream>>>(PA_r2o, PB_r2o, r2o_tgt, r2o_src, gb_r2o, gate_r2o);
  gate_kernel<<<NE / 8, 256, 0, stream>>>(PA_o2r, PB_o2r, o2r_tgt, o2r_src, gb_o2r, gate_o2r);

  segsum_kernel<<<N_OBJ, 256, 0, stream>>>(feat_reg, gate_r2o, r2o_src, off_r2o, m_obj);
  segsum_kernel<<<N_REG, 256, 0, stream>>>(feat_obj, gate_o2r, o2r_src, off_o2r, m_reg);

  // out = feat + relu(m) @ tw.T + tb
  gemm_mfma<true><<<dim3(D / 128, N_OBJ / 128), 256, 0, stream>>>(
      m_obj, D, btw_r2o, D, out_obj, D, feat_obj, tb_r2o, D);
  gemm_mfma<true><<<dim3(D / 128, N_REG / 128), 256, 0, stream>>>(
      m_reg, D, btw_o2r, D, out_reg, D, feat_reg, tb_o2r, D);
}

// Round 3
// 231.958 us; speedup vs baseline: 1.7387x; 1.2905x over previous
//
#include <hip/hip_runtime.h>

constexpr int N_OBJ = 4096, N_REG = 8192, D = 512, GW = 128, NE = 131072;

typedef __attribute__((ext_vector_type(8))) short short8;
typedef __attribute__((ext_vector_type(4))) float f32x4;

__device__ inline short f2bf(float f) {
  unsigned u = __builtin_bit_cast(unsigned, f);
  unsigned r = (u + 0x7FFF + ((u >> 16) & 1)) >> 16;
  return (short)r;
}
__device__ inline float bf2f(short s) {
  return __builtin_bit_cast(float, (unsigned)(((unsigned short)s) << 16));
}

// ---------- CSR offsets for BOTH edge lists (binary search over sorted tgt) ----------
__global__ void csr_all(const int* __restrict__ t_r2o, const int* __restrict__ t_o2r,
                        int* __restrict__ off_r2o, int* __restrict__ off_o2r) {
  int i = blockIdx.x * blockDim.x + threadIdx.x;
  const int* tgt; int* off; int t;
  if (i <= N_OBJ) { tgt = t_r2o; off = off_r2o; t = i; }
  else {
    i -= N_OBJ + 1;
    if (i > N_REG) return;
    tgt = t_o2r; off = off_o2r; t = i;
  }
  int lo = 0, hi = NE;
  while (lo < hi) {
    int mid = (lo + hi) >> 1;
    if (tgt[mid] < t) lo = mid + 1; else hi = mid;
  }
  off[t] = lo;
}

// ---------- one-pass cast: features -> {raw bf16, relu bf16}; weights -> combined bf16 ----------
// float4 units: feat_reg 1048576, feat_obj 524288, Wreg 32768, Wobj 32768, tw 65536 x2
__global__ __launch_bounds__(256) void cast_all(
    const float* __restrict__ feat_reg, const float* __restrict__ feat_obj,
    const float* __restrict__ gw_r2o, const float* __restrict__ gw_o2r,
    const float* __restrict__ tw_r2o, const float* __restrict__ tw_o2r,
    short* __restrict__ raw_reg, short* __restrict__ relu_reg,
    short* __restrict__ raw_obj, short* __restrict__ relu_obj,
    short* __restrict__ Wreg, short* __restrict__ Wobj,
    short* __restrict__ btw_r2o, short* __restrict__ btw_o2r) {
  int i = blockIdx.x * 256 + threadIdx.x;
  if (i < 1572864) {  // feature path: write raw + relu
    const float* src; short* draw; short* drelu; int j = i;
    if (j < 1048576) { src = feat_reg; draw = raw_reg; drelu = relu_reg; }
    else { j -= 1048576; src = feat_obj; draw = raw_obj; drelu = relu_obj; }
    float4 v = ((const float4*)src)[j];
    ((short4*)draw)[j] = make_short4(f2bf(v.x), f2bf(v.y), f2bf(v.z), f2bf(v.w));
    ((short4*)drelu)[j] = make_short4(f2bf(fmaxf(v.x, 0.f)), f2bf(fmaxf(v.y, 0.f)),
                                      f2bf(fmaxf(v.z, 0.f)), f2bf(fmaxf(v.w, 0.f)));
    return;
  }
  i -= 1572864;
  const float* src; short* dst; int di;
  if (i < 32768) {            // Wreg[j<128]=gw_r2o[j][:512]; [j>=128]=gw_o2r[j-128][512:]
    int row = i >> 7, c4 = i & 127;
    src = (row < 128) ? gw_r2o + (size_t)row * 1024 + c4 * 4
                      : gw_o2r + (size_t)(row - 128) * 1024 + 512 + c4 * 4;
    dst = Wreg; di = i;
  } else if (i < 65536) {     // Wobj[j<128]=gw_r2o[j][512:]; [j>=128]=gw_o2r[j-128][:512]
    int k = i - 32768, row = k >> 7, c4 = k & 127;
    src = (row < 128) ? gw_r2o + (size_t)row * 1024 + 512 + c4 * 4
                      : gw_o2r + (size_t)(row - 128) * 1024 + c4 * 4;
    dst = Wobj; di = k;
  } else if (i < 131072) { di = i - 65536; src = tw_r2o + (size_t)di * 4; dst = btw_r2o; }
  else                   { di = i - 131072; src = tw_o2r + (size_t)di * 4; dst = btw_o2r; }
  float4 v = *(const float4*)src;
  ((short4*)dst)[di] = make_short4(f2bf(v.x), f2bf(v.y), f2bf(v.z), f2bf(v.w));
}

// ---------- paired bf16 MFMA GEMM: two problems in one launch ----------
// C[m][n] = sum_k A[m,k]*B[n,k]; lda=ldb=K=512. EPI: fp32 C + res + bias; else bf16 C.
struct GemmPair {
  const short* A[2]; const short* B[2];
  const float* res[2]; const float* bias[2];
  void* C[2];
  int nb0;   // #blocks of problem 0
  int nxb;   // x-blocks (N/128)
  int ldc;
};

template<bool EPI>
__global__ __launch_bounds__(256) void gemm_pair(GemmPair gp) {
  __shared__ short As[128 * 32];
  __shared__ short Bs[128 * 32];
  int b = blockIdx.x;
  const int pi = (b >= gp.nb0) ? 1 : 0;
  if (pi) b -= gp.nb0;
  const int bx = b % gp.nxb, by = b / gp.nxb;
  const short* __restrict__ A = gp.A[pi];
  const short* __restrict__ B = gp.B[pi];
  const int ldc = gp.ldc;
  const int tid = threadIdx.x;
  const int lane = tid & 63, w = tid >> 6;
  const int m0 = by * 128, n0 = bx * 128;
  const int wm = (w >> 1) * 64, wn = (w & 1) * 64;
  const int sr = lane >> 2, sc = (lane & 3) * 8;
  const int fr = lane & 15, fk = (lane >> 4) * 8;

  f32x4 acc[4][4];
#pragma unroll
  for (int i = 0; i < 4; ++i)
#pragma unroll
    for (int j = 0; j < 4; ++j) acc[i][j] = (f32x4){0.f, 0.f, 0.f, 0.f};

  for (int k0 = 0; k0 < 512; k0 += 32) {
#pragma unroll
    for (int h = 0; h < 2; ++h) {
      int rg = w * 32 + h * 16;
      const short* ga = A + (size_t)(m0 + rg + sr) * 512 + k0 + sc;
      const short* gb = B + (size_t)(n0 + rg + sr) * 512 + k0 + sc;
      __builtin_amdgcn_global_load_lds(
          (const __attribute__((address_space(1))) void*)ga,
          (__attribute__((address_space(3))) void*)&As[rg * 32], 16, 0, 0);
      __builtin_amdgcn_global_load_lds(
          (const __attribute__((address_space(1))) void*)gb,
          (__attribute__((address_space(3))) void*)&Bs[rg * 32], 16, 0, 0);
    }
    __syncthreads();
    short8 a[4], bfr[4];
#pragma unroll
    for (int i = 0; i < 4; ++i)
      a[i] = *(const short8*)&As[(wm + i * 16 + fr) * 32 + fk];
#pragma unroll
    for (int j = 0; j < 4; ++j)
      bfr[j] = *(const short8*)&Bs[(wn + j * 16 + fr) * 32 + fk];
#pragma unroll
    for (int i = 0; i < 4; ++i)
#pragma unroll
      for (int j = 0; j < 4; ++j)
        acc[i][j] = __builtin_amdgcn_mfma_f32_16x16x32_bf16(a[i], bfr[j], acc[i][j], 0, 0, 0);
    __syncthreads();
  }

  if (EPI) {
    float* C = (float*)gp.C[pi];
    const float* res = gp.res[pi];
    const float* bias = gp.bias[pi];
#pragma unroll
    for (int i = 0; i < 4; ++i)
#pragma unroll
      for (int j = 0; j < 4; ++j) {
        int n = n0 + wn + j * 16 + fr;
#pragma unroll
        for (int r = 0; r < 4; ++r) {
          int m = m0 + wm + i * 16 + (lane >> 4) * 4 + r;
          C[(size_t)m * ldc + n] = acc[i][j][r] + res[(size_t)m * ldc + n] + bias[n];
        }
      }
  } else {
    short* C = (short*)gp.C[pi];
#pragma unroll
    for (int i = 0; i < 4; ++i)
#pragma unroll
      for (int j = 0; j < 4; ++j) {
        int n = n0 + wn + j * 16 + fr;
#pragma unroll
        for (int r = 0; r < 4; ++r) {
          int m = m0 + wm + i * 16 + (lane >> 4) * 4 + r;
          C[(size_t)m * ldc + n] = f2bf(acc[i][j][r]);
        }
      }
  }
}

// ---------- per-edge gate, both directions: mean_j sigmoid(PA[src][j]+PB[tgt][j]+gb[j]) ----------
__global__ __launch_bounds__(256) void gate2(
    const short* __restrict__ Preg, const short* __restrict__ Pobj,
    const int* __restrict__ r2o_tgt, const int* __restrict__ r2o_src,
    const int* __restrict__ o2r_tgt, const int* __restrict__ o2r_src,
    const float* __restrict__ gb_r2o, const float* __restrict__ gb_o2r,
    float* __restrict__ gate_r2o, float* __restrict__ gate_o2r) {
  const int tid = threadIdx.x, lane = tid & 31;
  const int e = blockIdx.x * 8 + (tid >> 5);
  const short* pa; const short* pb; const float* gbp; float* out;
  if (blockIdx.y == 0) {
    pa = Preg + (size_t)r2o_src[e] * 256 + lane * 4;
    pb = Pobj + (size_t)r2o_tgt[e] * 256 + lane * 4;
    gbp = gb_r2o; out = gate_r2o;
  } else {
    pa = Pobj + (size_t)o2r_src[e] * 256 + 128 + lane * 4;
    pb = Preg + (size_t)o2r_tgt[e] * 256 + 128 + lane * 4;
    gbp = gb_o2r; out = gate_o2r;
  }
  short4 a4 = *(const short4*)pa;
  short4 b4 = *(const short4*)pb;
  float4 bb = *(const float4*)&gbp[lane * 4];
  float sum = 1.f / (1.f + __expf(-(bf2f(a4.x) + bf2f(b4.x) + bb.x)))
            + 1.f / (1.f + __expf(-(bf2f(a4.y) + bf2f(b4.y) + bb.y)))
            + 1.f / (1.f + __expf(-(bf2f(a4.z) + bf2f(b4.z) + bb.z)))
            + 1.f / (1.f + __expf(-(bf2f(a4.w) + bf2f(b4.w) + bb.w)));
#pragma unroll
  for (int msk = 16; msk >= 1; msk >>= 1) sum += __shfl_xor(sum, msk, 64);
  if (lane == 0) out[e] = sum * (1.0f / GW);
}

// ---------- per-target segment mean (both directions); emits relu(m) bf16 ----------
__global__ __launch_bounds__(256) void segsum2(
    const short* __restrict__ raw_reg, const short* __restrict__ raw_obj,
    const float* __restrict__ gate_r2o, const float* __restrict__ gate_o2r,
    const int* __restrict__ r2o_src, const int* __restrict__ o2r_src,
    const int* __restrict__ off_r2o, const int* __restrict__ off_o2r,
    short* __restrict__ m_obj, short* __restrict__ m_reg) {
  int t = blockIdx.x;
  const short* ftab; const float* gate; const int* src; const int* off; short* mo;
  if (t < N_OBJ) { ftab = raw_reg; gate = gate_r2o; src = r2o_src; off = off_r2o; mo = m_obj; }
  else { t -= N_OBJ; ftab = raw_obj; gate = gate_o2r; src = o2r_src; off = off_o2r; mo = m_reg; }
  const int e0 = off[t], e1 = off[t + 1];
  const int tid = threadIdx.x;
  float a0 = 0.f, a1 = 0.f;
  for (int e = e0; e < e1; ++e) {
    float g = gate[e];
    int s = src[e];
    short2 v = *(const short2*)(ftab + (size_t)s * D + tid * 2);
    a0 += bf2f(v.x) * g;
    a1 += bf2f(v.y) * g;
  }
  float inv = 1.0f / fmaxf((float)(e1 - e0), 1.0f);
  short2 o;
  o.x = f2bf(fmaxf(a0 * inv, 0.f));
  o.y = f2bf(fmaxf(a1 * inv, 0.f));
  *(short2*)(mo + (size_t)t * D + tid * 2) = o;
}

extern "C" void kernel_launch(void* const* d_in, const int* in_sizes, int n_in,
                              void* d_out, int out_size, void* d_ws, size_t ws_size,
                              hipStream_t stream) {
  const float* feat_obj = (const float*)d_in[0];
  const float* feat_reg = (const float*)d_in[1];
  const int*   r2o_tgt  = (const int*)d_in[2];
  const int*   r2o_src  = (const int*)d_in[3];
  const int*   o2r_tgt  = (const int*)d_in[4];
  const int*   o2r_src  = (const int*)d_in[5];
  const float* gw_r2o   = (const float*)d_in[6];
  const float* gb_r2o   = (const float*)d_in[7];
  const float* gw_o2r   = (const float*)d_in[8];
  const float* gb_o2r   = (const float*)d_in[9];
  const float* tw_r2o   = (const float*)d_in[10];
  const float* tb_r2o   = (const float*)d_in[11];
  const float* tw_o2r   = (const float*)d_in[12];
  const float* tb_o2r   = (const float*)d_in[13];
  float* out_obj = (float*)d_out;
  float* out_reg = out_obj + (size_t)N_OBJ * D;

  size_t cur = 0;
  auto alloc = [&](size_t bytes) -> void* {
    cur = (cur + 255) & ~(size_t)255;
    void* p = (char*)d_ws + cur;
    cur += bytes;
    return p;
  };
  int*   off_r2o = (int*)alloc((N_OBJ + 1) * sizeof(int));
  int*   off_o2r = (int*)alloc((N_REG + 1) * sizeof(int));
  short* raw_reg = (short*)alloc((size_t)N_REG * D * 2);
  short* relu_reg= (short*)alloc((size_t)N_REG * D * 2);
  short* raw_obj = (short*)alloc((size_t)N_OBJ * D * 2);
  short* relu_obj= (short*)alloc((size_t)N_OBJ * D * 2);
  short* Wreg    = (short*)alloc((size_t)256 * D * 2);
  short* Wobj    = (short*)alloc((size_t)256 * D * 2);
  short* btw_r2o = (short*)alloc((size_t)D * D * 2);
  short* btw_o2r = (short*)alloc((size_t)D * D * 2);
  short* Preg    = (short*)alloc((size_t)N_REG * 256 * 2);
  short* Pobj    = (short*)alloc((size_t)N_OBJ * 256 * 2);
  float* gate_r2o= (float*)alloc((size_t)NE * 4);
  float* gate_o2r= (float*)alloc((size_t)NE * 4);
  short* m_obj   = (short*)alloc((size_t)N_OBJ * D * 2);
  short* m_reg   = (short*)alloc((size_t)N_REG * D * 2);

  csr_all<<<49, 256, 0, stream>>>(r2o_tgt, o2r_tgt, off_r2o, off_o2r);
  cast_all<<<6912, 256, 0, stream>>>(feat_reg, feat_obj, gw_r2o, gw_o2r, tw_r2o, tw_o2r,
                                     raw_reg, relu_reg, raw_obj, relu_obj,
                                     Wreg, Wobj, btw_r2o, btw_o2r);

  GemmPair proj;
  proj.A[0] = relu_reg; proj.B[0] = Wreg; proj.C[0] = Preg;
  proj.A[1] = relu_obj; proj.B[1] = Wobj; proj.C[1] = Pobj;
  proj.res[0] = proj.res[1] = nullptr; proj.bias[0] = proj.bias[1] = nullptr;
  proj.nb0 = 2 * (N_REG / 128); proj.nxb = 2; proj.ldc = 256;
  gemm_pair<false><<<192, 256, 0, stream>>>(proj);

  gate2<<<dim3(NE / 8, 2), 256, 0, stream>>>(Preg, Pobj, r2o_tgt, r2o_src, o2r_tgt, o2r_src,
                                             gb_r2o, gb_o2r, gate_r2o, gate_o2r);

  segsum2<<<N_OBJ + N_REG, 256, 0, stream>>>(raw_reg, raw_obj, gate_r2o, gate_o2r,
                                             r2o_src, o2r_src, off_r2o, off_o2r,
                                             m_obj, m_reg);

  GemmPair tr;
  tr.A[0] = m_reg; tr.B[0] = btw_o2r; tr.res[0] = feat_reg; tr.bias[0] = tb_o2r; tr.C[0] = out_reg;
  tr.A[1] = m_obj; tr.B[1] = btw_r2o; tr.res[1] = feat_obj; tr.bias[1] = tb_r2o; tr.C[1] = out_obj;
  tr.nb0 = 4 * (N_REG / 128); tr.nxb = 4; tr.ldc = D;
  gemm_pair<true><<<384, 256, 0, stream>>>(tr);
}

// Round 4
// 197.723 us; speedup vs baseline: 2.0397x; 1.1731x over previous
//
#include <hip/hip_runtime.h>

constexpr int N_OBJ = 4096, N_REG = 8192, D = 512, GW = 128, NE = 131072;

typedef __attribute__((ext_vector_type(8))) short short8;
typedef __attribute__((ext_vector_type(4))) float f32x4;

__device__ inline short f2bf(float f) {
  unsigned u = __builtin_bit_cast(unsigned, f);
  unsigned r = (u + 0x7FFF + ((u >> 16) & 1)) >> 16;
  return (short)r;
}
__device__ inline float bf2f(short s) {
  return __builtin_bit_cast(float, (unsigned)(((unsigned short)s) << 16));
}

// ---------- one-pass cast (features raw+relu, combined weights) + CSR offsets ----------
// float4 units: feat_reg 1048576, feat_obj 524288, Wreg 32768, Wobj 32768, tw 65536 x2
// = 1769472 threads (6912 blocks); blocks >= 6912 do the CSR binary searches.
__global__ __launch_bounds__(256) void cast_csr(
    const float* __restrict__ feat_reg, const float* __restrict__ feat_obj,
    const float* __restrict__ gw_r2o, const float* __restrict__ gw_o2r,
    const float* __restrict__ tw_r2o, const float* __restrict__ tw_o2r,
    const int* __restrict__ t_r2o, const int* __restrict__ t_o2r,
    short* __restrict__ raw_reg, short* __restrict__ relu_reg,
    short* __restrict__ raw_obj, short* __restrict__ relu_obj,
    short* __restrict__ Wreg, short* __restrict__ Wobj,
    short* __restrict__ btw_r2o, short* __restrict__ btw_o2r,
    int* __restrict__ off_r2o, int* __restrict__ off_o2r) {
  int i = blockIdx.x * 256 + threadIdx.x;
  if (i >= 1769472) {  // CSR tail blocks
    i -= 1769472;
    const int* tgt; int* off; int t;
    if (i <= N_OBJ) { tgt = t_r2o; off = off_r2o; t = i; }
    else {
      i -= N_OBJ + 1;
      if (i > N_REG) return;
      tgt = t_o2r; off = off_o2r; t = i;
    }
    int lo = 0, hi = NE;
    while (lo < hi) {
      int mid = (lo + hi) >> 1;
      if (tgt[mid] < t) lo = mid + 1; else hi = mid;
    }
    off[t] = lo;
    return;
  }
  if (i < 1572864) {  // feature path: write raw + relu
    const float* src; short* draw; short* drelu; int j = i;
    if (j < 1048576) { src = feat_reg; draw = raw_reg; drelu = relu_reg; }
    else { j -= 1048576; src = feat_obj; draw = raw_obj; drelu = relu_obj; }
    float4 v = ((const float4*)src)[j];
    ((short4*)draw)[j] = make_short4(f2bf(v.x), f2bf(v.y), f2bf(v.z), f2bf(v.w));
    ((short4*)drelu)[j] = make_short4(f2bf(fmaxf(v.x, 0.f)), f2bf(fmaxf(v.y, 0.f)),
                                      f2bf(fmaxf(v.z, 0.f)), f2bf(fmaxf(v.w, 0.f)));
    return;
  }
  i -= 1572864;
  const float* src; short* dst; int di;
  if (i < 32768) {            // Wreg[j<128]=gw_r2o[j][:512]; [j>=128]=gw_o2r[j-128][512:]
    int row = i >> 7, c4 = i & 127;
    src = (row < 128) ? gw_r2o + (size_t)row * 1024 + c4 * 4
                      : gw_o2r + (size_t)(row - 128) * 1024 + 512 + c4 * 4;
    dst = Wreg; di = i;
  } else if (i < 65536) {     // Wobj[j<128]=gw_r2o[j][512:]; [j>=128]=gw_o2r[j-128][:512]
    int k = i - 32768, row = k >> 7, c4 = k & 127;
    src = (row < 128) ? gw_r2o + (size_t)row * 1024 + 512 + c4 * 4
                      : gw_o2r + (size_t)(row - 128) * 1024 + c4 * 4;
    dst = Wobj; di = k;
  } else if (i < 131072) { di = i - 65536; src = tw_r2o + (size_t)di * 4; dst = btw_r2o; }
  else                   { di = i - 131072; src = tw_o2r + (size_t)di * 4; dst = btw_o2r; }
  float4 v = *(const float4*)src;
  ((short4*)dst)[di] = make_short4(f2bf(v.x), f2bf(v.y), f2bf(v.z), f2bf(v.w));
}

// ---------- paired bf16 MFMA GEMM: two problems in one launch ----------
struct GemmPair {
  const short* A[2]; const short* B[2];
  const float* res[2]; const float* bias[2];
  void* C[2];
  int nb0;   // #blocks of problem 0
  int nxb;   // x-blocks (N/128)
  int ldc;
};

template<bool EPI>
__global__ __launch_bounds__(256) void gemm_pair(GemmPair gp) {
  __shared__ short As[128 * 32];
  __shared__ short Bs[128 * 32];
  int b = blockIdx.x;
  const int pi = (b >= gp.nb0) ? 1 : 0;
  if (pi) b -= gp.nb0;
  const int bx = b % gp.nxb, by = b / gp.nxb;
  const short* __restrict__ A = gp.A[pi];
  const short* __restrict__ B = gp.B[pi];
  const int ldc = gp.ldc;
  const int tid = threadIdx.x;
  const int lane = tid & 63, w = tid >> 6;
  const int m0 = by * 128, n0 = bx * 128;
  const int wm = (w >> 1) * 64, wn = (w & 1) * 64;
  const int sr = lane >> 2, sc = (lane & 3) * 8;
  const int fr = lane & 15, fk = (lane >> 4) * 8;

  f32x4 acc[4][4];
#pragma unroll
  for (int i = 0; i < 4; ++i)
#pragma unroll
    for (int j = 0; j < 4; ++j) acc[i][j] = (f32x4){0.f, 0.f, 0.f, 0.f};

  for (int k0 = 0; k0 < 512; k0 += 32) {
#pragma unroll
    for (int h = 0; h < 2; ++h) {
      int rg = w * 32 + h * 16;
      const short* ga = A + (size_t)(m0 + rg + sr) * 512 + k0 + sc;
      const short* gb = B + (size_t)(n0 + rg + sr) * 512 + k0 + sc;
      __builtin_amdgcn_global_load_lds(
          (const __attribute__((address_space(1))) void*)ga,
          (__attribute__((address_space(3))) void*)&As[rg * 32], 16, 0, 0);
      __builtin_amdgcn_global_load_lds(
          (const __attribute__((address_space(1))) void*)gb,
          (__attribute__((address_space(3))) void*)&Bs[rg * 32], 16, 0, 0);
    }
    __syncthreads();
    short8 a[4], bfr[4];
#pragma unroll
    for (int i = 0; i < 4; ++i)
      a[i] = *(const short8*)&As[(wm + i * 16 + fr) * 32 + fk];
#pragma unroll
    for (int j = 0; j < 4; ++j)
      bfr[j] = *(const short8*)&Bs[(wn + j * 16 + fr) * 32 + fk];
#pragma unroll
    for (int i = 0; i < 4; ++i)
#pragma unroll
      for (int j = 0; j < 4; ++j)
        acc[i][j] = __builtin_amdgcn_mfma_f32_16x16x32_bf16(a[i], bfr[j], acc[i][j], 0, 0, 0);
    __syncthreads();
  }

  if (EPI) {
    float* C = (float*)gp.C[pi];
    const float* res = gp.res[pi];
    const float* bias = gp.bias[pi];
#pragma unroll
    for (int i = 0; i < 4; ++i)
#pragma unroll
      for (int j = 0; j < 4; ++j) {
        int n = n0 + wn + j * 16 + fr;
#pragma unroll
        for (int r = 0; r < 4; ++r) {
          int m = m0 + wm + i * 16 + (lane >> 4) * 4 + r;
          C[(size_t)m * ldc + n] = acc[i][j][r] + res[(size_t)m * ldc + n] + bias[n];
        }
      }
  } else {
    short* C = (short*)gp.C[pi];
#pragma unroll
    for (int i = 0; i < 4; ++i)
#pragma unroll
      for (int j = 0; j < 4; ++j) {
        int n = n0 + wn + j * 16 + fr;
#pragma unroll
        for (int r = 0; r < 4; ++r) {
          int m = m0 + wm + i * 16 + (lane >> 4) * 4 + r;
          C[(size_t)m * ldc + n] = f2bf(acc[i][j][r]);
        }
      }
  }
}

// ---------- FUSED gate + segment-mean, both directions ----------
// One block per target. PB[tgt]+bias cached in registers (loaded once).
// 4 waves each take every 4th edge; per edge: gate = mean sigmoid(PA[src]+PB+gb)
// via 64-lane butterfly, then acc += gate * feat_row (short8/lane = 1KB/wave).
// Cross-wave LDS reduce at the end; emits relu(mean) as bf16.
__global__ __launch_bounds__(256) void fused_msg(
    const short* __restrict__ Preg, const short* __restrict__ Pobj,
    const short* __restrict__ raw_reg, const short* __restrict__ raw_obj,
    const int* __restrict__ r2o_src, const int* __restrict__ o2r_src,
    const int* __restrict__ off_r2o, const int* __restrict__ off_o2r,
    const float* __restrict__ gb_r2o, const float* __restrict__ gb_o2r,
    short* __restrict__ m_obj, short* __restrict__ m_reg) {
  __shared__ float red[4][512];
  int t = blockIdx.x;
  const short* PA; const short* PB; const short* feat; const int* src;
  const int* off; const float* gb; short* mo; int po;
  if (t < N_OBJ) {
    PA = Preg; PB = Pobj; feat = raw_reg; src = r2o_src; off = off_r2o;
    gb = gb_r2o; mo = m_obj; po = 0;
  } else {
    t -= N_OBJ;
    PA = Pobj; PB = Preg; feat = raw_obj; src = o2r_src; off = off_o2r;
    gb = gb_o2r; mo = m_reg; po = 128;
  }
  const int tid = threadIdx.x, lane = tid & 63, w = tid >> 6;
  const int e0 = off[t], e1 = off[t + 1];
  // per-target constants: PB row (128 bf16) + gate bias, 2 lanes' worth each
  short2 pb2 = *(const short2*)&PB[(size_t)t * 256 + po + lane * 2];
  float2 gb2 = *(const float2*)&gb[lane * 2];
  const float c0 = bf2f(pb2.x) + gb2.x, c1 = bf2f(pb2.y) + gb2.y;
  float acc[8] = {};
  for (int e = e0 + w; e < e1; e += 4) {
    int s = src[e];
    short2 pa2 = *(const short2*)&PA[(size_t)s * 256 + po + lane * 2];
    short8 v = *(const short8*)&feat[(size_t)s * 512 + lane * 8];
    float gs = 1.f / (1.f + __expf(-(bf2f(pa2.x) + c0)))
             + 1.f / (1.f + __expf(-(bf2f(pa2.y) + c1)));
#pragma unroll
    for (int msk = 32; msk >= 1; msk >>= 1) gs += __shfl_xor(gs, msk, 64);
    gs *= (1.0f / 128.0f);
#pragma unroll
    for (int j = 0; j < 8; ++j) acc[j] += bf2f(v[j]) * gs;
  }
  *(float4*)&red[w][lane * 8]     = (float4){acc[0], acc[1], acc[2], acc[3]};
  *(float4*)&red[w][lane * 8 + 4] = (float4){acc[4], acc[5], acc[6], acc[7]};
  __syncthreads();
  const float inv = 1.0f / fmaxf((float)(e1 - e0), 1.0f);
  const int d = tid * 2;
  float s0 = red[0][d] + red[1][d] + red[2][d] + red[3][d];
  float s1 = red[0][d + 1] + red[1][d + 1] + red[2][d + 1] + red[3][d + 1];
  short2 o;
  o.x = f2bf(fmaxf(s0 * inv, 0.f));
  o.y = f2bf(fmaxf(s1 * inv, 0.f));
  *(short2*)(mo + (size_t)t * 512 + d) = o;
}

extern "C" void kernel_launch(void* const* d_in, const int* in_sizes, int n_in,
                              void* d_out, int out_size, void* d_ws, size_t ws_size,
                              hipStream_t stream) {
  const float* feat_obj = (const float*)d_in[0];
  const float* feat_reg = (const float*)d_in[1];
  const int*   r2o_tgt  = (const int*)d_in[2];
  const int*   r2o_src  = (const int*)d_in[3];
  const int*   o2r_tgt  = (const int*)d_in[4];
  const int*   o2r_src  = (const int*)d_in[5];
  const float* gw_r2o   = (const float*)d_in[6];
  const float* gb_r2o   = (const float*)d_in[7];
  const float* gw_o2r   = (const float*)d_in[8];
  const float* gb_o2r   = (const float*)d_in[9];
  const float* tw_r2o   = (const float*)d_in[10];
  const float* tb_r2o   = (const float*)d_in[11];
  const float* tw_o2r   = (const float*)d_in[12];
  const float* tb_o2r   = (const float*)d_in[13];
  float* out_obj = (float*)d_out;
  float* out_reg = out_obj + (size_t)N_OBJ * D;

  size_t cur = 0;
  auto alloc = [&](size_t bytes) -> void* {
    cur = (cur + 255) & ~(size_t)255;
    void* p = (char*)d_ws + cur;
    cur += bytes;
    return p;
  };
  int*   off_r2o = (int*)alloc((N_OBJ + 1) * sizeof(int));
  int*   off_o2r = (int*)alloc((N_REG + 1) * sizeof(int));
  short* raw_reg = (short*)alloc((size_t)N_REG * D * 2);
  short* relu_reg= (short*)alloc((size_t)N_REG * D * 2);
  short* raw_obj = (short*)alloc((size_t)N_OBJ * D * 2);
  short* relu_obj= (short*)alloc((size_t)N_OBJ * D * 2);
  short* Wreg    = (short*)alloc((size_t)256 * D * 2);
  short* Wobj    = (short*)alloc((size_t)256 * D * 2);
  short* btw_r2o = (short*)alloc((size_t)D * D * 2);
  short* btw_o2r = (short*)alloc((size_t)D * D * 2);
  short* Preg    = (short*)alloc((size_t)N_REG * 256 * 2);
  short* Pobj    = (short*)alloc((size_t)N_OBJ * 256 * 2);
  short* m_obj   = (short*)alloc((size_t)N_OBJ * D * 2);
  short* m_reg   = (short*)alloc((size_t)N_REG * D * 2);

  cast_csr<<<6961, 256, 0, stream>>>(feat_reg, feat_obj, gw_r2o, gw_o2r, tw_r2o, tw_o2r,
                                     r2o_tgt, o2r_tgt,
                                     raw_reg, relu_reg, raw_obj, relu_obj,
                                     Wreg, Wobj, btw_r2o, btw_o2r, off_r2o, off_o2r);

  GemmPair proj;
  proj.A[0] = relu_reg; proj.B[0] = Wreg; proj.C[0] = Preg;
  proj.A[1] = relu_obj; proj.B[1] = Wobj; proj.C[1] = Pobj;
  proj.res[0] = proj.res[1] = nullptr; proj.bias[0] = proj.bias[1] = nullptr;
  proj.nb0 = 2 * (N_REG / 128); proj.nxb = 2; proj.ldc = 256;
  gemm_pair<false><<<192, 256, 0, stream>>>(proj);

  fused_msg<<<N_OBJ + N_REG, 256, 0, stream>>>(Preg, Pobj, raw_reg, raw_obj,
                                               r2o_src, o2r_src, off_r2o, off_o2r,
                                               gb_r2o, gb_o2r, m_obj, m_reg);

  GemmPair tr;
  tr.A[0] = m_reg; tr.B[0] = btw_o2r; tr.res[0] = feat_reg; tr.bias[0] = tb_o2r; tr.C[0] = out_reg;
  tr.A[1] = m_obj; tr.B[1] = btw_r2o; tr.res[1] = feat_obj; tr.bias[1] = tb_r2o; tr.C[1] = out_obj;
  tr.nb0 = 4 * (N_REG / 128); tr.nxb = 4; tr.ldc = D;
  gemm_pair<true><<<384, 256, 0, stream>>>(tr);
}

// Round 5
// 185.953 us; speedup vs baseline: 2.1688x; 1.0633x over previous
//
#include <hip/hip_runtime.h>

constexpr int N_OBJ = 4096, N_REG = 8192, D = 512, GW = 128, NE = 131072;

typedef __attribute__((ext_vector_type(8))) short short8;
typedef __attribute__((ext_vector_type(4))) float f32x4;
typedef __attribute__((ext_vector_type(2))) float f32x2;

__device__ inline short f2bf(float f) {
  unsigned u = __builtin_bit_cast(unsigned, f);
  unsigned r = (u + 0x7FFF + ((u >> 16) & 1)) >> 16;
  return (short)r;
}
__device__ inline float bf2f(short s) {
  return __builtin_bit_cast(float, (unsigned)(((unsigned short)s) << 16));
}

// ---------- one-pass cast (features raw-fp8 + relu-bf16, combined weights bf16) + CSR ----------
// float4 units: feat_reg 1048576, feat_obj 524288, Wreg 32768, Wobj 32768, tw 65536 x2
// = 1769472 threads; tail threads do the CSR binary searches.
__global__ __launch_bounds__(256) void cast_csr(
    const float* __restrict__ feat_reg, const float* __restrict__ feat_obj,
    const float* __restrict__ gw_r2o, const float* __restrict__ gw_o2r,
    const float* __restrict__ tw_r2o, const float* __restrict__ tw_o2r,
    const int* __restrict__ t_r2o, const int* __restrict__ t_o2r,
    unsigned char* __restrict__ raw_reg, short* __restrict__ relu_reg,
    unsigned char* __restrict__ raw_obj, short* __restrict__ relu_obj,
    short* __restrict__ Wreg, short* __restrict__ Wobj,
    short* __restrict__ btw_r2o, short* __restrict__ btw_o2r,
    int* __restrict__ off_r2o, int* __restrict__ off_o2r) {
  int i = blockIdx.x * 256 + threadIdx.x;
  if (i >= 1769472) {  // CSR tail
    i -= 1769472;
    const int* tgt; int* off; int t;
    if (i <= N_OBJ) { tgt = t_r2o; off = off_r2o; t = i; }
    else {
      i -= N_OBJ + 1;
      if (i > N_REG) return;
      tgt = t_o2r; off = off_o2r; t = i;
    }
    int lo = 0, hi = NE;
    while (lo < hi) {
      int mid = (lo + hi) >> 1;
      if (tgt[mid] < t) lo = mid + 1; else hi = mid;
    }
    off[t] = lo;
    return;
  }
  if (i < 1572864) {  // feature path: raw fp8 + relu bf16
    const float* src; unsigned char* draw; short* drelu; int j = i;
    if (j < 1048576) { src = feat_reg; draw = raw_reg; drelu = relu_reg; }
    else { j -= 1048576; src = feat_obj; draw = raw_obj; drelu = relu_obj; }
    float4 v = ((const float4*)src)[j];
    int p = __builtin_amdgcn_cvt_pk_fp8_f32(v.x, v.y, 0, false);
    p = __builtin_amdgcn_cvt_pk_fp8_f32(v.z, v.w, p, true);
    ((unsigned*)draw)[j] = (unsigned)p;
    ((short4*)drelu)[j] = make_short4(f2bf(fmaxf(v.x, 0.f)), f2bf(fmaxf(v.y, 0.f)),
                                      f2bf(fmaxf(v.z, 0.f)), f2bf(fmaxf(v.w, 0.f)));
    return;
  }
  i -= 1572864;
  const float* src; short* dst; int di;
  if (i < 32768) {            // Wreg[j<128]=gw_r2o[j][:512]; [j>=128]=gw_o2r[j-128][512:]
    int row = i >> 7, c4 = i & 127;
    src = (row < 128) ? gw_r2o + (size_t)row * 1024 + c4 * 4
                      : gw_o2r + (size_t)(row - 128) * 1024 + 512 + c4 * 4;
    dst = Wreg; di = i;
  } else if (i < 65536) {     // Wobj[j<128]=gw_r2o[j][512:]; [j>=128]=gw_o2r[j-128][:512]
    int k = i - 32768, row = k >> 7, c4 = k & 127;
    src = (row < 128) ? gw_r2o + (size_t)row * 1024 + 512 + c4 * 4
                      : gw_o2r + (size_t)(row - 128) * 1024 + c4 * 4;
    dst = Wobj; di = k;
  } else if (i < 131072) { di = i - 65536; src = tw_r2o + (size_t)di * 4; dst = btw_r2o; }
  else                   { di = i - 131072; src = tw_o2r + (size_t)di * 4; dst = btw_o2r; }
  float4 v = *(const float4*)src;
  ((short4*)dst)[di] = make_short4(f2bf(v.x), f2bf(v.y), f2bf(v.z), f2bf(v.w));
}

// ---------- paired bf16 MFMA GEMM: two problems in one launch ----------
// EPI: fp32 C = acc + res + bias. !EPI: fp8 C (projection outputs).
struct GemmPair {
  const short* A[2]; const short* B[2];
  const float* res[2]; const float* bias[2];
  void* C[2];
  int nb0;   // #blocks of problem 0
  int nxb;   // x-blocks (N/128)
  int ldc;
};

template<bool EPI>
__global__ __launch_bounds__(256) void gemm_pair(GemmPair gp) {
  __shared__ short As[128 * 32];
  __shared__ short Bs[128 * 32];
  int b = blockIdx.x;
  const int pi = (b >= gp.nb0) ? 1 : 0;
  if (pi) b -= gp.nb0;
  const int bx = b % gp.nxb, by = b / gp.nxb;
  const short* __restrict__ A = gp.A[pi];
  const short* __restrict__ B = gp.B[pi];
  const int ldc = gp.ldc;
  const int tid = threadIdx.x;
  const int lane = tid & 63, w = tid >> 6;
  const int m0 = by * 128, n0 = bx * 128;
  const int wm = (w >> 1) * 64, wn = (w & 1) * 64;
  const int sr = lane >> 2, sc = (lane & 3) * 8;
  const int fr = lane & 15, fk = (lane >> 4) * 8;

  f32x4 acc[4][4];
#pragma unroll
  for (int i = 0; i < 4; ++i)
#pragma unroll
    for (int j = 0; j < 4; ++j) acc[i][j] = (f32x4){0.f, 0.f, 0.f, 0.f};

  for (int k0 = 0; k0 < 512; k0 += 32) {
#pragma unroll
    for (int h = 0; h < 2; ++h) {
      int rg = w * 32 + h * 16;
      const short* ga = A + (size_t)(m0 + rg + sr) * 512 + k0 + sc;
      const short* gb = B + (size_t)(n0 + rg + sr) * 512 + k0 + sc;
      __builtin_amdgcn_global_load_lds(
          (const __attribute__((address_space(1))) void*)ga,
          (__attribute__((address_space(3))) void*)&As[rg * 32], 16, 0, 0);
      __builtin_amdgcn_global_load_lds(
          (const __attribute__((address_space(1))) void*)gb,
          (__attribute__((address_space(3))) void*)&Bs[rg * 32], 16, 0, 0);
    }
    __syncthreads();
    short8 a[4], bfr[4];
#pragma unroll
    for (int i = 0; i < 4; ++i)
      a[i] = *(const short8*)&As[(wm + i * 16 + fr) * 32 + fk];
#pragma unroll
    for (int j = 0; j < 4; ++j)
      bfr[j] = *(const short8*)&Bs[(wn + j * 16 + fr) * 32 + fk];
#pragma unroll
    for (int i = 0; i < 4; ++i)
#pragma unroll
      for (int j = 0; j < 4; ++j)
        acc[i][j] = __builtin_amdgcn_mfma_f32_16x16x32_bf16(a[i], bfr[j], acc[i][j], 0, 0, 0);
    __syncthreads();
  }

  if (EPI) {
    float* C = (float*)gp.C[pi];
    const float* res = gp.res[pi];
    const float* bias = gp.bias[pi];
#pragma unroll
    for (int i = 0; i < 4; ++i)
#pragma unroll
      for (int j = 0; j < 4; ++j) {
        int n = n0 + wn + j * 16 + fr;
#pragma unroll
        for (int r = 0; r < 4; ++r) {
          int m = m0 + wm + i * 16 + (lane >> 4) * 4 + r;
          C[(size_t)m * ldc + n] = acc[i][j][r] + res[(size_t)m * ldc + n] + bias[n];
        }
      }
  } else {
    unsigned char* C = (unsigned char*)gp.C[pi];
#pragma unroll
    for (int i = 0; i < 4; ++i)
#pragma unroll
      for (int j = 0; j < 4; ++j) {
        int n = n0 + wn + j * 16 + fr;
#pragma unroll
        for (int r = 0; r < 4; ++r) {
          int m = m0 + wm + i * 16 + (lane >> 4) * 4 + r;
          int pk = __builtin_amdgcn_cvt_pk_fp8_f32(acc[i][j][r], acc[i][j][r], 0, false);
          C[(size_t)m * ldc + n] = (unsigned char)(pk & 0xFF);
        }
      }
  }
}

// ---------- FUSED gate + segment-mean, both directions, fp8 gathers ----------
// One block (4 waves) per target; each 32-lane HALF-WAVE owns an edge:
// lane l: 4 gate elems (j=l*4..l*4+3) + 16 feature elems (d=l*16..l*16+15).
// gate via 5-step butterfly within the half; halves merged once post-loop.
__global__ __launch_bounds__(256) void fused_msg(
    const unsigned char* __restrict__ Preg, const unsigned char* __restrict__ Pobj,
    const unsigned char* __restrict__ raw_reg, const unsigned char* __restrict__ raw_obj,
    const int* __restrict__ r2o_src, const int* __restrict__ o2r_src,
    const int* __restrict__ off_r2o, const int* __restrict__ off_o2r,
    const float* __restrict__ gb_r2o, const float* __restrict__ gb_o2r,
    short* __restrict__ m_obj, short* __restrict__ m_reg) {
  __shared__ float red[4][512];
  int t = blockIdx.x;
  const unsigned char *PA, *PB, *feat; const int *src, *off; const float* gb;
  short* mo; int po;
  if (t < N_OBJ) {
    PA = Preg; PB = Pobj; feat = raw_reg; src = r2o_src; off = off_r2o;
    gb = gb_r2o; mo = m_obj; po = 0;
  } else {
    t -= N_OBJ;
    PA = Pobj; PB = Preg; feat = raw_obj; src = o2r_src; off = off_o2r;
    gb = gb_o2r; mo = m_reg; po = 128;
  }
  const int tid = threadIdx.x, lane = tid & 63, w = tid >> 6;
  const int hw = lane >> 5, l = lane & 31;
  const int e0 = off[t], e1 = off[t + 1];
  // per-target constants: PB[t] row (fp8) + gate bias, 4 elems/lane
  unsigned pbu = *(const unsigned*)&PB[(size_t)t * 256 + po + l * 4];
  f32x2 pb01 = __builtin_amdgcn_cvt_pk_f32_fp8((int)pbu, false);
  f32x2 pb23 = __builtin_amdgcn_cvt_pk_f32_fp8((int)pbu, true);
  float4 gbv = *(const float4*)&gb[l * 4];
  const float c0 = pb01.x + gbv.x, c1 = pb01.y + gbv.y;
  const float c2 = pb23.x + gbv.z, c3 = pb23.y + gbv.w;
  float acc[16] = {};
  for (int e = e0 + w * 2 + hw; e < e1; e += 8) {
    int s = src[e];
    unsigned pau = *(const unsigned*)&PA[(size_t)s * 256 + po + l * 4];
    uint4 fv = *(const uint4*)&feat[(size_t)s * 512 + l * 16];
    f32x2 a01 = __builtin_amdgcn_cvt_pk_f32_fp8((int)pau, false);
    f32x2 a23 = __builtin_amdgcn_cvt_pk_f32_fp8((int)pau, true);
    float gs = 1.f / (1.f + __expf(-(a01.x + c0)))
             + 1.f / (1.f + __expf(-(a01.y + c1)))
             + 1.f / (1.f + __expf(-(a23.x + c2)))
             + 1.f / (1.f + __expf(-(a23.y + c3)));
#pragma unroll
    for (int msk = 16; msk >= 1; msk >>= 1) gs += __shfl_xor(gs, msk, 64);
    f32x2 f0 = __builtin_amdgcn_cvt_pk_f32_fp8((int)fv.x, false);
    f32x2 f1 = __builtin_amdgcn_cvt_pk_f32_fp8((int)fv.x, true);
    f32x2 f2 = __builtin_amdgcn_cvt_pk_f32_fp8((int)fv.y, false);
    f32x2 f3 = __builtin_amdgcn_cvt_pk_f32_fp8((int)fv.y, true);
    f32x2 f4 = __builtin_amdgcn_cvt_pk_f32_fp8((int)fv.z, false);
    f32x2 f5 = __builtin_amdgcn_cvt_pk_f32_fp8((int)fv.z, true);
    f32x2 f6 = __builtin_amdgcn_cvt_pk_f32_fp8((int)fv.w, false);
    f32x2 f7 = __builtin_amdgcn_cvt_pk_f32_fp8((int)fv.w, true);
    acc[0]  += f0.x * gs; acc[1]  += f0.y * gs;
    acc[2]  += f1.x * gs; acc[3]  += f1.y * gs;
    acc[4]  += f2.x * gs; acc[5]  += f2.y * gs;
    acc[6]  += f3.x * gs; acc[7]  += f3.y * gs;
    acc[8]  += f4.x * gs; acc[9]  += f4.y * gs;
    acc[10] += f5.x * gs; acc[11] += f5.y * gs;
    acc[12] += f6.x * gs; acc[13] += f6.y * gs;
    acc[14] += f7.x * gs; acc[15] += f7.y * gs;
  }
  // merge the two half-waves (lane l <-> l+32), then half 0 writes LDS
#pragma unroll
  for (int jj = 0; jj < 16; ++jj) acc[jj] += __shfl_xor(acc[jj], 32, 64);
  if (hw == 0) {
#pragma unroll
    for (int q = 0; q < 4; ++q)
      *(float4*)&red[w][l * 16 + q * 4] =
          (float4){acc[q * 4], acc[q * 4 + 1], acc[q * 4 + 2], acc[q * 4 + 3]};
  }
  __syncthreads();
  // cross-wave reduce; fold the 1/128 gate-mean factor into inv
  const float inv = (1.0f / 128.0f) / fmaxf((float)(e1 - e0), 1.0f);
  const int d = tid * 2;
  float s0 = red[0][d] + red[1][d] + red[2][d] + red[3][d];
  float s1 = red[0][d + 1] + red[1][d + 1] + red[2][d + 1] + red[3][d + 1];
  short2 o;
  o.x = f2bf(fmaxf(s0 * inv, 0.f));
  o.y = f2bf(fmaxf(s1 * inv, 0.f));
  *(short2*)(mo + (size_t)t * 512 + d) = o;
}

extern "C" void kernel_launch(void* const* d_in, const int* in_sizes, int n_in,
                              void* d_out, int out_size, void* d_ws, size_t ws_size,
                              hipStream_t stream) {
  const float* feat_obj = (const float*)d_in[0];
  const float* feat_reg = (const float*)d_in[1];
  const int*   r2o_tgt  = (const int*)d_in[2];
  const int*   r2o_src  = (const int*)d_in[3];
  const int*   o2r_tgt  = (const int*)d_in[4];
  const int*   o2r_src  = (const int*)d_in[5];
  const float* gw_r2o   = (const float*)d_in[6];
  const float* gb_r2o   = (const float*)d_in[7];
  const float* gw_o2r   = (const float*)d_in[8];
  const float* gb_o2r   = (const float*)d_in[9];
  const float* tw_r2o   = (const float*)d_in[10];
  const float* tb_r2o   = (const float*)d_in[11];
  const float* tw_o2r   = (const float*)d_in[12];
  const float* tb_o2r   = (const float*)d_in[13];
  float* out_obj = (float*)d_out;
  float* out_reg = out_obj + (size_t)N_OBJ * D;

  size_t cur = 0;
  auto alloc = [&](size_t bytes) -> void* {
    cur = (cur + 255) & ~(size_t)255;
    void* p = (char*)d_ws + cur;
    cur += bytes;
    return p;
  };
  int*   off_r2o = (int*)alloc((N_OBJ + 1) * sizeof(int));
  int*   off_o2r = (int*)alloc((N_REG + 1) * sizeof(int));
  unsigned char* raw_reg = (unsigned char*)alloc((size_t)N_REG * D);   // fp8
  unsigned char* raw_obj = (unsigned char*)alloc((size_t)N_OBJ * D);   // fp8
  short* relu_reg= (short*)alloc((size_t)N_REG * D * 2);
  short* relu_obj= (short*)alloc((size_t)N_OBJ * D * 2);
  short* Wreg    = (short*)alloc((size_t)256 * D * 2);
  short* Wobj    = (short*)alloc((size_t)256 * D * 2);
  short* btw_r2o = (short*)alloc((size_t)D * D * 2);
  short* btw_o2r = (short*)alloc((size_t)D * D * 2);
  unsigned char* Preg = (unsigned char*)alloc((size_t)N_REG * 256);    // fp8
  unsigned char* Pobj = (unsigned char*)alloc((size_t)N_OBJ * 256);    // fp8
  short* m_obj   = (short*)alloc((size_t)N_OBJ * D * 2);
  short* m_reg   = (short*)alloc((size_t)N_REG * D * 2);

  cast_csr<<<6961, 256, 0, stream>>>(feat_reg, feat_obj, gw_r2o, gw_o2r, tw_r2o, tw_o2r,
                                     r2o_tgt, o2r_tgt,
                                     raw_reg, relu_reg, raw_obj, relu_obj,
                                     Wreg, Wobj, btw_r2o, btw_o2r, off_r2o, off_o2r);

  GemmPair proj;
  proj.A[0] = relu_reg; proj.B[0] = Wreg; proj.C[0] = Preg;
  proj.A[1] = relu_obj; proj.B[1] = Wobj; proj.C[1] = Pobj;
  proj.res[0] = proj.res[1] = nullptr; proj.bias[0] = proj.bias[1] = nullptr;
  proj.nb0 = 2 * (N_REG / 128); proj.nxb = 2; proj.ldc = 256;
  gemm_pair<false><<<192, 256, 0, stream>>>(proj);

  fused_msg<<<N_OBJ + N_REG, 256, 0, stream>>>(Preg, Pobj, raw_reg, raw_obj,
                                               r2o_src, o2r_src, off_r2o, off_o2r,
                                               gb_r2o, gb_o2r, m_obj, m_reg);

  GemmPair tr;
  tr.A[0] = m_reg; tr.B[0] = btw_o2r; tr.res[0] = feat_reg; tr.bias[0] = tb_o2r; tr.C[0] = out_reg;
  tr.A[1] = m_obj; tr.B[1] = btw_r2o; tr.res[1] = feat_obj; tr.bias[1] = tb_r2o; tr.C[1] = out_obj;
  tr.nb0 = 4 * (N_REG / 128); tr.nxb = 4; tr.ldc = D;
  gemm_pair<true><<<384, 256, 0, stream>>>(tr);
}